// Round 1
// 272.038 us; speedup vs baseline: 1.3419x; 1.3419x over previous
//
#include <hip/hip_runtime.h>
#include <stdint.h>

#define D_DIM 1024
#define M_DIM 128
#define BR 64
#define BD 64

// Bit-exact semantics (verified R7, absmax=0.0):
//   h[r][m]  = sequential __fmaf_rn chain over d = 0..1023 (ascending)
//   FWHT stages on column-bit 0,1,...,6 ascending; out[bit]=a+b / a-b, fp32
//   bit = (h > 0) ? 1.0f : 0.0f
//
// R8: stage global->LDS via __builtin_amdgcn_global_load_lds (width 16).
//   - kills the 48-float/thread staging registers that were spilling to
//     scratch (WRITE_SIZE was 393 MB vs 16.8 MB of real output)
//   - LDS dest must be linear (wave base + lane*16), so the W tile is
//     bank-deswizzled via the GLOBAL source address instead of a +1 pad:
//     logical chunk (r, cj) -> physical chunk r*16 + (cj ^ ((r>>2)&15)).
//     Read side applies the same XOR -> 8 bank-quads x 4 lanes = b128 floor.
//   - X tile reads are tg-broadcast (2 unique addrs/instr) -> linear, no swizzle.
// Block: 256 threads = 32 col-quads x 8 row-groups. Tile 64 rows x 128 cols.

typedef const __attribute__((address_space(1))) void* gas_cptr;
typedef __attribute__((address_space(3))) void* lds_vptr;

__device__ __forceinline__ void gload_lds16(const float* g, float* l) {
    __builtin_amdgcn_global_load_lds((gas_cptr)g, (lds_vptr)l, 16, 0, 0);
}

__global__ __launch_bounds__(256, 3)
void rewa_kernel(const float* __restrict__ X, const float* __restrict__ W,
                 float* __restrict__ out) {
    #pragma clang fp contract(off)
    __shared__ float wsh[M_DIM * BD];   // 32 KB, chunk-swizzled (see above)
    __shared__ float xs[BR * BD];       // 16 KB, linear [r][j]

    const int t    = threadIdx.x;
    const int lane = t & 63;
    const int wave = t >> 6;       // 0..3
    const int tc   = t & 31;       // col quad -> cols 4tc..4tc+3
    const int tg   = t >> 5;       // row group -> rows 8tg..8tg+7
    const size_t row0 = (size_t)blockIdx.x * BR;

    // Per-lane global source pointers. W source pre-applies the inverse
    // of the read-side XOR swizzle; LDS destinations stay linear.
    const float* wsrc[8];
    #pragma unroll
    for (int q = 0; q < 8; ++q) {
        const int inst = wave * 8 + q;            // 0..31
        const int r    = inst * 4 + (lane >> 4);  // W row 0..127
        const int cj   = (lane & 15) ^ (inst & 15);
        wsrc[q] = W + (size_t)r * D_DIM + 4 * cj;
    }
    const float* xsrc[4];
    #pragma unroll
    for (int q = 0; q < 4; ++q) {
        const int inst = wave * 4 + q;            // 0..15
        const int r    = inst * 4 + (lane >> 4);  // X tile row 0..63
        xsrc[q] = X + (row0 + r) * D_DIM + 4 * (lane & 15);
    }

    float acc[4][8];
    #pragma unroll
    for (int ci = 0; ci < 4; ++ci)
        #pragma unroll
        for (int rr = 0; rr < 8; ++rr) acc[ci][rr] = 0.0f;

    for (int d0 = 0; d0 < D_DIM; d0 += BD) {
        __syncthreads();               // previous chunk's LDS reads done
        // global -> LDS, no register round-trip
        #pragma unroll
        for (int q = 0; q < 8; ++q)
            gload_lds16(wsrc[q] + d0, &wsh[(wave * 8 + q) * 256]);
        #pragma unroll
        for (int q = 0; q < 4; ++q)
            gload_lds16(xsrc[q] + d0, &xs[(wave * 4 + q) * 256]);
        __syncthreads();               // implies s_waitcnt vmcnt(0): tile visible

        // compute: j ascending (bit-exact chain order)
        #pragma unroll 4
        for (int j4 = 0; j4 < BD; j4 += 4) {
            float4 wf[4], xf[8];
            const int pw = (((j4 >> 2) ^ (tc & 15)) << 2);  // swizzled float offs
            #pragma unroll
            for (int ci = 0; ci < 4; ++ci)
                wf[ci] = *(const float4*)&wsh[(4 * tc + ci) * BD + pw];
            #pragma unroll
            for (int rr = 0; rr < 8; ++rr)
                xf[rr] = *(const float4*)&xs[(8 * tg + rr) * BD + j4];
            #pragma unroll
            for (int e = 0; e < 4; ++e) {
                #pragma unroll
                for (int rr = 0; rr < 8; ++rr) {
                    const float xv = ((const float*)&xf[rr])[e];
                    #pragma unroll
                    for (int ci = 0; ci < 4; ++ci)
                        acc[ci][rr] = __fmaf_rn(xv, ((const float*)&wf[ci])[e],
                                                acc[ci][rr]);
                }
            }
        }
    }

    // ---- FWHT, fp32, ascending column bits. col = 4*tc + ci ----
    // bits 0,1 live in ci (register butterflies, FIRST)
    #pragma unroll
    for (int rr = 0; rr < 8; ++rr) {
        const float a0 = acc[0][rr], a1 = acc[1][rr];
        const float a2 = acc[2][rr], a3 = acc[3][rr];
        const float b0 = __fadd_rn(a0, a1), b1 = __fsub_rn(a0, a1);   // bit 0
        const float b2 = __fadd_rn(a2, a3), b3 = __fsub_rn(a2, a3);
        acc[0][rr] = __fadd_rn(b0, b2);                                // bit 1
        acc[1][rr] = __fadd_rn(b1, b3);
        acc[2][rr] = __fsub_rn(b0, b2);
        acc[3][rr] = __fsub_rn(b1, b3);
    }
    // bits 2..6 live in tc = lane bits 0..4 (same tg on both shuffle ends)
    #pragma unroll
    for (int h = 1; h <= 16; h <<= 1) {
        const bool up = (tc & h) != 0;
        #pragma unroll
        for (int ci = 0; ci < 4; ++ci)
            #pragma unroll
            for (int rr = 0; rr < 8; ++rr) {
                const float mine  = acc[ci][rr];
                const float other = __shfl_xor(mine, h, 64);
                acc[ci][rr] = up ? __fsub_rn(other, mine)
                                 : __fadd_rn(mine, other);
            }
    }

    // sign + coalesced float4 store
    #pragma unroll
    for (int rr = 0; rr < 8; ++rr) {
        float4 v;
        v.x = (acc[0][rr] > 0.0f) ? 1.0f : 0.0f;
        v.y = (acc[1][rr] > 0.0f) ? 1.0f : 0.0f;
        v.z = (acc[2][rr] > 0.0f) ? 1.0f : 0.0f;
        v.w = (acc[3][rr] > 0.0f) ? 1.0f : 0.0f;
        *(float4*)(out + (row0 + 8 * tg + rr) * M_DIM + 4 * tc) = v;
    }
}

extern "C" void kernel_launch(void* const* d_in, const int* in_sizes, int n_in,
                              void* d_out, int out_size, void* d_ws, size_t ws_size,
                              hipStream_t stream) {
    const float* x = (const float*)d_in[0];
    const float* W = (const float*)d_in[1];
    float* out = (float*)d_out;
    const int nrows = out_size / M_DIM;   // 32768

    hipLaunchKernelGGL(rewa_kernel, dim3(nrows / BR), dim3(256), 0, stream,
                       x, W, out);
}